// Round 15
// baseline (100.095 us; speedup 1.0000x reference)
//
#include <hip/hip_runtime.h>
#include <hip/hip_fp16.h>

#define B 32
#define O 64
#define M 128
#define H 4
#define E 64
#define SC 2.88539008177792681f     // 2*log2(e): tanh(x) = 1 - 2/(1+exp2(SC*x))
#define LOG2E 1.44269504088896341f
#define SSTR 68                     // s_S row stride (dwords): 4-aligned, (4m+e)%32 banks
#define ESTR 65                     // s_E row stride (dwords/half2): (e+col)%32 banks

#if __has_builtin(__builtin_amdgcn_exp2f)
#define EXP2F(x) __builtin_amdgcn_exp2f(x)
#else
#define EXP2F(x) __exp2f(x)
#endif

__device__ __forceinline__ float rl(float v, int lane) {
    return __uint_as_float(__builtin_amdgcn_readlane(__float_as_uint(v), lane));
}
__device__ __forceinline__ unsigned pk2h(float a, float b) {
    return (unsigned)__half_as_ushort(__float2half_rn(a)) |
           ((unsigned)__half_as_ushort(__float2half_rn(b)) << 16);
}

// ============ single fused kernel: 1024 blocks = (b, o-pair) ============
__global__ __launch_bounds__(256) void attn_fused(
    const float* __restrict__ query,   // [B,O,E]
    const float* __restrict__ context, // [B,M,E]
    const float* __restrict__ memory,  // [B,M,E]
    const float* __restrict__ W_ch,    // [E, H*E]
    const float* __restrict__ b_ch,    // [H*E]
    const float* __restrict__ w_logit, // [E]
    const float* __restrict__ b_logit, // [1]
    const float* __restrict__ W_rh,    // [H*E, E]
    const float* __restrict__ b_rh,    // [E]
    const float* __restrict__ temp,    // [1]
    float* __restrict__ out)           // [B,O,E]
{
    __shared__ float    s_S[M * SSTR];   // 34816 B scratch: ctx f32, then mem f32
    __shared__ unsigned s_E[E * ESTR];   // 16640 B: exp-space ctx fp16, [e][m-pair]
    __shared__ float    s_po0[4 * E];    // 1 KB out partials o0
    __shared__ float    s_po1[4 * E];    // 1 KB             -> 52.25 KB, 3 blocks/CU

    const int t = threadIdx.x, lane = t & 63, w = t >> 6;
    const int bo0 = blockIdx.x * 2, bo1 = bo0 + 1, b = bo0 >> 6;

    // ---- phase 1: stage ctx f32 -> s_S (coalesced float4, stride-68 rows) ----
    {
        const float* ctx = context + b * (M * E);
        #pragma unroll
        for (int i = 0; i < 8; ++i) {
            int idx = i * 1024 + t * 4;
            float4 v = *(const float4*)(ctx + idx);
            *(float4*)(&s_S[(idx >> 6) * SSTR + (idx & 63)]) = v;
        }
    }
    // ---- q projection in registers (overlaps staging): c = t = w*64+lane ----
    float qE0, qE1;
    {
        float qq0 = query[bo0 * E + lane];     // lane k holds query[bo0][k]
        float qq1 = query[bo1 * E + lane];
        float acc0 = b_ch[t], acc1 = acc0;
        const float* Wc = W_ch + t;
        #pragma unroll 16
        for (int k = 0; k < 64; ++k) {
            float wv = Wc[k * 256];
            acc0 = fmaf(rl(qq0, k), wv, acc0);
            acc1 = fmaf(rl(qq1, k), wv, acc1);
        }
        qE0 = EXP2F(SC * acc0);
        qE1 = EXP2F(SC * acc1);
    }
    const float wl = w_logit[lane];
    float sumw = wl;
    #pragma unroll
    for (int sft = 1; sft < 64; sft <<= 1) sumw += __shfl_xor(sumw, sft);
    const float bl   = b_logit[0];
    const float lsc  = LOG2E / temp[0];
    const float base = (sumw + bl) * lsc;   // logit = base + lsc2*acc
    const float lsc2 = -2.0f * lsc;
    __syncthreads();   // ctx staged

    // ---- phase 2: transpose + exp2 -> s_E fp16 [e][m-pair], stride 65 dw ----
    // thread: e = lane, cols w*16..w*16+15. read bank (4m+lane)%32, write (lane+col)%32.
    {
        const int e = lane, c0 = w * 16;
        #pragma unroll
        for (int k = 0; k < 16; ++k) {
            int m0 = 2 * (c0 + k);
            float ea = fminf(EXP2F(SC * s_S[m0 * SSTR + e]), 60000.f);
            float eb = fminf(EXP2F(SC * s_S[(m0 + 1) * SSTR + e]), 60000.f);
            s_E[e * ESTR + c0 + k] = pk2h(ea, eb);
        }
    }
    __syncthreads();   // s_E ready; s_S free for reuse

    // ---- phase 3: stage mem f32 -> s_S (writes drain during tanh loop) ----
    {
        const float* mem = memory + b * (M * E);
        #pragma unroll
        for (int i = 0; i < 8; ++i) {
            int idx = i * 1024 + t * 4;
            float4 v = *(const float4*)(mem + idx);
            *(float4*)(&s_S[(idx >> 6) * SSTR + (idx & 63)]) = v;
        }
    }

    // ---- tanh+logit: wave w = head, lane covers m = 2*lane, 2*lane+1, both o's ----
    float a00 = 0.f, a01 = 0.f, a10 = 0.f, a11 = 0.f;
    #pragma unroll 4
    for (int e = 0; e < 64; ++e) {
        __half2 c2 = *(const __half2*)&s_E[e * ESTR + lane];   // bank (e+lane)%32 free
        float2 cf = __half22float2(c2);
        float q0 = rl(qE0, e);
        float q1 = rl(qE1, e);
        float we = rl(wl, e);
        float t00 = fmaf(cf.x, q0, 1.0f);
        float t01 = fmaf(cf.y, q0, 1.0f);
        float t10 = fmaf(cf.x, q1, 1.0f);
        float t11 = fmaf(cf.y, q1, 1.0f);
        float r0 = __builtin_amdgcn_rcpf(t00 * t01);
        float r1 = __builtin_amdgcn_rcpf(t10 * t11);
        float w0 = we * r0;
        float w1 = we * r1;
        a00 = fmaf(w0, t01, a00);  a01 = fmaf(w0, t00, a01);
        a10 = fmaf(w1, t11, a10);  a11 = fmaf(w1, t10, a11);
    }

    // ---- softmax (register-resident, unnormalized probs) ----
    float l00 = fmaf(lsc2, a00, base), l01 = fmaf(lsc2, a01, base);
    float l10 = fmaf(lsc2, a10, base), l11 = fmaf(lsc2, a11, base);
    float mx0 = fmaxf(l00, l01), mx1 = fmaxf(l10, l11);
    #pragma unroll
    for (int sft = 1; sft < 64; sft <<= 1) {
        mx0 = fmaxf(mx0, __shfl_xor(mx0, sft));
        mx1 = fmaxf(mx1, __shfl_xor(mx1, sft));
    }
    float e00 = EXP2F(l00 - mx0), e01 = EXP2F(l01 - mx0);
    float e10 = EXP2F(l10 - mx1), e11 = EXP2F(l11 - mx1);
    float s0 = e00 + e01, s1 = e10 + e11;
    #pragma unroll
    for (int sft = 1; sft < 64; sft <<= 1) {
        s0 += __shfl_xor(s0, sft);
        s1 += __shfl_xor(s1, sft);
    }
    float rs0 = __builtin_amdgcn_rcpf(s0), rs1 = __builtin_amdgcn_rcpf(s1);
    __syncthreads();   // mem staged (phase 3 writes visible)

    // ---- heads: wave w = its own head over all m; mem f32 from s_S ----
    float h0 = 0.f, h1 = 0.f;
    #pragma unroll 8
    for (int j = 0; j < 64; ++j) {
        float mv0 = s_S[(2 * j) * SSTR + lane];        // bank (8j+lane)%32, 2-way free
        float mv1 = s_S[(2 * j + 1) * SSTR + lane];
        float p00 = rl(e00, j), p01 = rl(e01, j);
        float p10 = rl(e10, j), p11 = rl(e11, j);
        h0 = fmaf(p00, mv0, h0); h0 = fmaf(p01, mv1, h0);
        h1 = fmaf(p10, mv0, h1); h1 = fmaf(p11, mv1, h1);
    }
    float hv0 = h0 * rs0;
    float hv1 = h1 * rs1;
    hv0 = (hv0 > 0.f) ? hv0 : 0.01f * hv0;   // leaky relu; heads[h=w][e=lane]
    hv1 = (hv1 > 0.f) ? hv1 : 0.01f * hv1;

    // ---- fused output projection: wave w owns W_rh rows w*64..w*64+63 ----
    {
        float acc0 = 0.f, acc1 = 0.f;
        const float* Wp = W_rh + (w * 64) * 64 + lane;
        #pragma unroll 8
        for (int jj = 0; jj < 64; ++jj) {
            float wv = Wp[jj * 64];
            acc0 = fmaf(rl(hv0, jj), wv, acc0);
            acc1 = fmaf(rl(hv1, jj), wv, acc1);
        }
        s_po0[w * 64 + lane] = acc0;
        s_po1[w * 64 + lane] = acc1;
    }
    __syncthreads();
    if (t < 64) {
        float o = s_po0[t] + s_po0[64 + t] + s_po0[128 + t] + s_po0[192 + t] + b_rh[t];
        out[(size_t)bo0 * 64 + t] = o;
    } else if (t < 128) {
        int e2 = t - 64;
        float o = s_po1[e2] + s_po1[64 + e2] + s_po1[128 + e2] + s_po1[192 + e2] + b_rh[e2];
        out[(size_t)bo1 * 64 + e2] = o;
    }
}

extern "C" void kernel_launch(void* const* d_in, const int* in_sizes, int n_in,
                              void* d_out, int out_size, void* d_ws, size_t ws_size,
                              hipStream_t stream) {
    const float* query   = (const float*)d_in[0];
    const float* context = (const float*)d_in[1];
    const float* memory  = (const float*)d_in[2];
    const float* W_ch    = (const float*)d_in[3];
    const float* b_ch    = (const float*)d_in[4];
    const float* w_logit = (const float*)d_in[5];
    const float* b_logit = (const float*)d_in[6];
    const float* W_rh    = (const float*)d_in[7];
    const float* b_rh    = (const float*)d_in[8];
    const float* temp    = (const float*)d_in[9];
    float* out = (float*)d_out;

    attn_fused<<<B * O / 2, 256, 0, stream>>>(query, context, memory, W_ch, b_ch,
                                              w_logit, b_logit, W_rh, b_rh, temp, out);
}